// Round 1
// baseline (274.602 us; speedup 1.0000x reference)
//
#include <hip/hip_runtime.h>
#include <stdint.h>

#define D_MODEL 1024
#define NHEAD 16
#define HD 64
#define BB 2
#define TT 2048
#define MR (BB*TT)   // 4096 rows

typedef unsigned short u16;
typedef __bf16 bf16x8 __attribute__((ext_vector_type(8)));
typedef u16 u16x8 __attribute__((ext_vector_type(8)));
typedef float f32x4 __attribute__((ext_vector_type(4)));

__device__ __forceinline__ u16 f2bf(float f) {
  union { float f; unsigned u; } v; v.f = f;
  unsigned r = v.u + 0x7FFFu + ((v.u >> 16) & 1u);
  return (u16)(r >> 16);
}

__device__ __forceinline__ void gload_lds16(const void* g, void* l) {
  __builtin_amdgcn_global_load_lds(
      (const __attribute__((address_space(1))) void*)g,
      (__attribute__((address_space(3))) void*)l, 16, 0, 0);
}

// ---------------- f32 -> bf16 convert (vectorized) ----------------
__global__ void k_f32_to_bf16(const float* __restrict__ src, u16* __restrict__ dst, int n4) {
  int idx = blockIdx.x * blockDim.x + threadIdx.x;
  int stride = gridDim.x * blockDim.x;
  for (int i = idx; i < n4; i += stride) {
    float4 v = reinterpret_cast<const float4*>(src)[i];
    ushort4 o;
    o.x = f2bf(v.x); o.y = f2bf(v.y); o.z = f2bf(v.z); o.w = f2bf(v.w);
    reinterpret_cast<ushort4*>(dst)[i] = o;
  }
}

// ---------------- transpose f32 [K][N] -> bf16 [N][K] ----------------
__global__ void k_transpose_f32_bf16(const float* __restrict__ src, u16* __restrict__ dst,
                                     int K, int N) {
  __shared__ float tile[32][33];
  int n0 = blockIdx.x * 32, k0 = blockIdx.y * 32;
  int tx = threadIdx.x, ty = threadIdx.y;  // block (32,8)
  #pragma unroll
  for (int i = 0; i < 32; i += 8)
    tile[ty + i][tx] = src[(size_t)(k0 + ty + i) * N + n0 + tx];
  __syncthreads();
  #pragma unroll
  for (int i = 0; i < 32; i += 8)
    dst[(size_t)(n0 + ty + i) * K + k0 + tx] = f2bf(tile[tx][ty + i]);
}

// ---------------- bf16 GEMM, B^T input, 128x128 tile ----------------
// MODE 0: qkv projection -> scatter into Q/K/V [B][H][T][64] bf16, +bias
// MODE 1: out = A @ B + bias, f32 row-major
template<int MODE>
__global__ __launch_bounds__(256)
void k_gemm_bt(const u16* __restrict__ A, const u16* __restrict__ Bt,
               const float* __restrict__ bias,
               u16* __restrict__ q_out, u16* __restrict__ k_out, u16* __restrict__ v_out,
               float* __restrict__ c_out, int M, int N, int K)
{
  __shared__ __align__(16) u16 a_sh[128 * 64];
  __shared__ __align__(16) u16 b_sh[128 * 64];
  const int u = threadIdx.x;
  const int lane = u & 63;
  const int w = u >> 6;
  const int wr = w >> 1, wc = w & 1;
  const int m0 = blockIdx.y * 128;
  const int n0 = blockIdx.x * 128;
  const int r = lane & 15, q4 = lane >> 4;

  f32x4 acc[4][4];
  #pragma unroll
  for (int i = 0; i < 4; i++)
    #pragma unroll
    for (int j = 0; j < 4; j++) acc[i][j] = {0.f, 0.f, 0.f, 0.f};

  const int arow = u >> 3;        // 0..31
  const int acol = (u & 7) * 8;   // 0..56
  const u16* Ag = A + (size_t)(m0 + arow) * K + acol;
  const u16* Bg = Bt + (size_t)(n0 + arow) * K + acol;

  for (int k0 = 0; k0 < K; k0 += 64) {
    #pragma unroll
    for (int i = 0; i < 4; i++) {
      gload_lds16(Ag + (size_t)i * 32 * K + k0, &a_sh[(i * 32 + w * 8) * 64]);
      gload_lds16(Bg + (size_t)i * 32 * K + k0, &b_sh[(i * 32 + w * 8) * 64]);
    }
    __syncthreads();
    #pragma unroll
    for (int kc = 0; kc < 2; kc++) {
      bf16x8 af[4], bfr[4];
      #pragma unroll
      for (int m = 0; m < 4; m++)
        af[m] = *reinterpret_cast<const bf16x8*>(&a_sh[(wr * 64 + m * 16 + r) * 64 + kc * 32 + q4 * 8]);
      #pragma unroll
      for (int n = 0; n < 4; n++)
        bfr[n] = *reinterpret_cast<const bf16x8*>(&b_sh[(wc * 64 + n * 16 + r) * 64 + kc * 32 + q4 * 8]);
      #pragma unroll
      for (int m = 0; m < 4; m++)
        #pragma unroll
        for (int n = 0; n < 4; n++)
          acc[m][n] = __builtin_amdgcn_mfma_f32_16x16x32_bf16(af[m], bfr[n], acc[m][n], 0, 0, 0);
    }
    __syncthreads();
  }

  if (MODE == 0) {
    #pragma unroll
    for (int n = 0; n < 4; n++) {
      int gcol = n0 + wc * 64 + n * 16 + r;
      int which = gcol >> 10;
      int rem = gcol & 1023;
      int h = rem >> 6, d = rem & 63;
      u16* dst = (which == 0) ? q_out : ((which == 1) ? k_out : v_out);
      float bv = bias[gcol];
      #pragma unroll
      for (int m = 0; m < 4; m++) {
        #pragma unroll
        for (int reg = 0; reg < 4; reg++) {
          int grow = m0 + wr * 64 + m * 16 + q4 * 4 + reg;
          int b = grow >> 11, t = grow & 2047;
          dst[(((size_t)(b * NHEAD + h) * TT + t) << 6) + d] = f2bf(acc[m][n][reg] + bv);
        }
      }
    }
  } else {
    #pragma unroll
    for (int m = 0; m < 4; m++) {
      #pragma unroll
      for (int reg = 0; reg < 4; reg++) {
        int grow = m0 + wr * 64 + m * 16 + q4 * 4 + reg;
        #pragma unroll
        for (int n = 0; n < 4; n++) {
          int gcol = n0 + wc * 64 + n * 16 + r;
          c_out[(size_t)grow * N + gcol] = acc[m][n][reg] + bias[gcol];
        }
      }
    }
  }
}

// ---------------- causal flash attention ----------------
// grid: (T/64, B*H), block: 256 (4 waves). Wave w: q rows [qt*64+w*16, +16)
__global__ __launch_bounds__(256)
void k_attn(const u16* __restrict__ Q, const u16* __restrict__ Kk,
            const u16* __restrict__ V, u16* __restrict__ Y)
{
  __shared__ __align__(16) u16 k_sh[64 * 64];
  __shared__ __align__(16) u16 vt_sh[64 * 72];      // V transposed [d][k], padded
  __shared__ __align__(16) u16 p_sh[4][16 * 72];    // per-wave P [q][k], padded

  const int u = threadIdx.x;
  const int lane = u & 63;
  const int w = u >> 6;
  const int r = lane & 15, q4 = lane >> 4;
  const int qt = blockIdx.x;
  const int bh = blockIdx.y;
  const int b = bh >> 4, h = bh & 15;
  const size_t head_off = (size_t)bh * TT * HD;

  // Q fragments held in registers for the whole block
  const int qrow = qt * 64 + w * 16 + r;
  bf16x8 qf[2];
  qf[0] = *reinterpret_cast<const bf16x8*>(&Q[head_off + (size_t)qrow * HD + q4 * 8]);
  qf[1] = *reinterpret_cast<const bf16x8*>(&Q[head_off + (size_t)qrow * HD + 32 + q4 * 8]);

  f32x4 of[4];
  #pragma unroll
  for (int i = 0; i < 4; i++) of[i] = {0.f, 0.f, 0.f, 0.f};
  float m_run[4], l_run[4];
  #pragma unroll
  for (int i = 0; i < 4; i++) { m_run[i] = -1e30f; l_run[i] = 0.f; }

  const int srow = u >> 3;        // 0..31
  const int scol = (u & 7) * 8;   // 0..56

  for (int kt = 0; kt <= qt; kt++) {
    // stage K tile (64x64) via global_load_lds, linear layout
    #pragma unroll
    for (int i = 0; i < 2; i++)
      gload_lds16(&Kk[head_off + (size_t)(kt * 64 + i * 32 + srow) * HD + scol],
                  &k_sh[(i * 32 + w * 8) * 64]);
    // stage V tile transposed: vt_sh[d][k]
    #pragma unroll
    for (int i = 0; i < 2; i++) {
      u16x8 vv = *reinterpret_cast<const u16x8*>(
          &V[head_off + (size_t)(kt * 64 + i * 32 + srow) * HD + scol]);
      #pragma unroll
      for (int j = 0; j < 8; j++)
        vt_sh[(scol + j) * 72 + i * 32 + srow] = vv[j];
    }
    __syncthreads();

    // S = Q K^T  (per wave: 16 q-rows x 64 k-cols)
    f32x4 sf[4];
    #pragma unroll
    for (int n = 0; n < 4; n++) {
      f32x4 a = {0.f, 0.f, 0.f, 0.f};
      #pragma unroll
      for (int kc = 0; kc < 2; kc++) {
        bf16x8 kf = *reinterpret_cast<const bf16x8*>(&k_sh[(n * 16 + r) * 64 + kc * 32 + q4 * 8]);
        a = __builtin_amdgcn_mfma_f32_16x16x32_bf16(qf[kc], kf, a, 0, 0, 0);
      }
      sf[n] = a;
    }
    // scale + causal mask (diag tile only)
    #pragma unroll
    for (int n = 0; n < 4; n++) {
      #pragma unroll
      for (int reg = 0; reg < 4; reg++) {
        float s = sf[n][reg] * 0.125f;
        if (kt == qt) {
          int ql = w * 16 + q4 * 4 + reg;
          int kl = n * 16 + r;
          if (kl > ql) s = -1e30f;
        }
        sf[n][reg] = s;
      }
    }
    // row max across 4 frags + 16 lanes
    float alpha[4];
    #pragma unroll
    for (int reg = 0; reg < 4; reg++) {
      float v = fmaxf(fmaxf(sf[0][reg], sf[1][reg]), fmaxf(sf[2][reg], sf[3][reg]));
      #pragma unroll
      for (int off = 1; off < 16; off <<= 1) v = fmaxf(v, __shfl_xor(v, off));
      float mnew = fmaxf(m_run[reg], v);
      alpha[reg] = __expf(m_run[reg] - mnew);
      m_run[reg] = mnew;
    }
    // P = exp(S - m), row sum
    float rs[4] = {0.f, 0.f, 0.f, 0.f};
    #pragma unroll
    for (int n = 0; n < 4; n++) {
      #pragma unroll
      for (int reg = 0; reg < 4; reg++) {
        float p = __expf(sf[n][reg] - m_run[reg]);
        sf[n][reg] = p;
        rs[reg] += p;
      }
    }
    #pragma unroll
    for (int reg = 0; reg < 4; reg++) {
      float v = rs[reg];
      #pragma unroll
      for (int off = 1; off < 16; off <<= 1) v += __shfl_xor(v, off);
      l_run[reg] = l_run[reg] * alpha[reg] + v;
    }
    #pragma unroll
    for (int d0 = 0; d0 < 4; d0++)
      #pragma unroll
      for (int reg = 0; reg < 4; reg++)
        of[d0][reg] *= alpha[reg];

    // transpose P into A-fragment layout via per-wave LDS
    #pragma unroll
    for (int n = 0; n < 4; n++)
      #pragma unroll
      for (int reg = 0; reg < 4; reg++)
        p_sh[w][(q4 * 4 + reg) * 72 + n * 16 + r] = f2bf(sf[n][reg]);
    __syncthreads();

    // O += P @ V
    #pragma unroll
    for (int kc = 0; kc < 2; kc++) {
      bf16x8 pa = *reinterpret_cast<const bf16x8*>(&p_sh[w][r * 72 + kc * 32 + q4 * 8]);
      #pragma unroll
      for (int d0 = 0; d0 < 4; d0++) {
        bf16x8 vb = *reinterpret_cast<const bf16x8*>(&vt_sh[(d0 * 16 + r) * 72 + kc * 32 + q4 * 8]);
        of[d0] = __builtin_amdgcn_mfma_f32_16x16x32_bf16(pa, vb, of[d0], 0, 0, 0);
      }
    }
    __syncthreads();  // protect k_sh / vt_sh before next tile's staging
  }

  // epilogue: Y[(b*T + t)*1024 + h*64 + d], bf16
  #pragma unroll
  for (int d0 = 0; d0 < 4; d0++) {
    #pragma unroll
    for (int reg = 0; reg < 4; reg++) {
      int t = qt * 64 + w * 16 + q4 * 4 + reg;
      float val = of[d0][reg] / l_run[reg];
      Y[((size_t)(b * TT + t) << 10) + h * 64 + d0 * 16 + r] = f2bf(val);
    }
  }
}

// ---------------- host launcher ----------------
extern "C" void kernel_launch(void* const* d_in, const int* in_sizes, int n_in,
                              void* d_out, int out_size, void* d_ws, size_t ws_size,
                              hipStream_t stream) {
  const float* x     = (const float*)d_in[0];
  const float* w_qkv = (const float*)d_in[1];
  const float* b_qkv = (const float*)d_in[2];
  const float* w_out = (const float*)d_in[3];
  const float* b_out = (const float*)d_in[4];
  float* out = (float*)d_out;

  uint8_t* ws = (uint8_t*)d_ws;
  u16* xb    = (u16*)(ws);                    // 8 MB  (reused as y_heads later)
  u16* wqkvT = (u16*)(ws + (8u  << 20));      // 6 MB
  u16* woutT = (u16*)(ws + (14u << 20));      // 2 MB
  u16* Qh    = (u16*)(ws + (16u << 20));      // 8 MB
  u16* Kh    = (u16*)(ws + (24u << 20));      // 8 MB
  u16* Vh    = (u16*)(ws + (32u << 20));      // 8 MB  (total 40 MB)

  k_f32_to_bf16<<<1024, 256, 0, stream>>>(x, xb, (MR * D_MODEL) / 4);
  k_transpose_f32_bf16<<<dim3(3 * D_MODEL / 32, D_MODEL / 32), dim3(32, 8), 0, stream>>>(
      w_qkv, wqkvT, D_MODEL, 3 * D_MODEL);
  k_transpose_f32_bf16<<<dim3(D_MODEL / 32, D_MODEL / 32), dim3(32, 8), 0, stream>>>(
      w_out, woutT, D_MODEL, D_MODEL);

  k_gemm_bt<0><<<dim3(3 * D_MODEL / 128, MR / 128), 256, 0, stream>>>(
      xb, wqkvT, b_qkv, Qh, Kh, Vh, nullptr, MR, 3 * D_MODEL, D_MODEL);

  u16* Yh = xb;  // reuse x-bf16 region
  k_attn<<<dim3(TT / 64, BB * NHEAD), 256, 0, stream>>>(Qh, Kh, Vh, Yh);

  k_gemm_bt<1><<<dim3(D_MODEL / 128, MR / 128), 256, 0, stream>>>(
      Yh, woutT, b_out, nullptr, nullptr, nullptr, out, MR, D_MODEL, D_MODEL);
}

// Round 2
// 229.949 us; speedup vs baseline: 1.1942x; 1.1942x over previous
//
#include <hip/hip_runtime.h>
#include <stdint.h>

#define D_MODEL 1024
#define NHEAD 16
#define HD 64
#define BB 2
#define TT 2048
#define MR (BB*TT)   // 4096 rows

typedef unsigned short u16;
typedef __bf16 bf16x8 __attribute__((ext_vector_type(8)));
typedef u16 u16x8 __attribute__((ext_vector_type(8)));
typedef float f32x4 __attribute__((ext_vector_type(4)));

__device__ __forceinline__ u16 f2bf(float f) {
  union { float f; unsigned u; } v; v.f = f;
  unsigned r = v.u + 0x7FFFu + ((v.u >> 16) & 1u);
  return (u16)(r >> 16);
}

__device__ __forceinline__ void gload_lds16(const void* g, void* l) {
  __builtin_amdgcn_global_load_lds(
      (const __attribute__((address_space(1))) void*)g,
      (__attribute__((address_space(3))) void*)l, 16, 0, 0);
}

// ---------------- f32 -> bf16 convert (vectorized) ----------------
__global__ void k_f32_to_bf16(const float* __restrict__ src, u16* __restrict__ dst, int n4) {
  int idx = blockIdx.x * blockDim.x + threadIdx.x;
  int stride = gridDim.x * blockDim.x;
  for (int i = idx; i < n4; i += stride) {
    float4 v = reinterpret_cast<const float4*>(src)[i];
    ushort4 o;
    o.x = f2bf(v.x); o.y = f2bf(v.y); o.z = f2bf(v.z); o.w = f2bf(v.w);
    reinterpret_cast<ushort4*>(dst)[i] = o;
  }
}

// ---------------- transpose f32 [K][N] -> bf16 [N][K] ----------------
__global__ void k_transpose_f32_bf16(const float* __restrict__ src, u16* __restrict__ dst,
                                     int K, int N) {
  __shared__ float tile[32][33];
  int n0 = blockIdx.x * 32, k0 = blockIdx.y * 32;
  int tx = threadIdx.x, ty = threadIdx.y;  // block (32,8)
  #pragma unroll
  for (int i = 0; i < 32; i += 8)
    tile[ty + i][tx] = src[(size_t)(k0 + ty + i) * N + n0 + tx];
  __syncthreads();
  #pragma unroll
  for (int i = 0; i < 32; i += 8)
    dst[(size_t)(n0 + ty + i) * K + k0 + tx] = f2bf(tile[tx][ty + i]);
}

// ---------------- bf16 GEMM, B^T input, 128x128 tile ----------------
// MODE 0: qkv projection -> scatter Q/K into [B][H][T][64], V into [B][H][64][T] (transposed), +bias
// MODE 1: out = A @ B + bias, f32 row-major
template<int MODE>
__global__ __launch_bounds__(256)
void k_gemm_bt(const u16* __restrict__ A, const u16* __restrict__ Bt,
               const float* __restrict__ bias,
               u16* __restrict__ q_out, u16* __restrict__ k_out, u16* __restrict__ v_out,
               float* __restrict__ c_out, int M, int N, int K)
{
  __shared__ __align__(16) u16 a_sh[128 * 64];
  __shared__ __align__(16) u16 b_sh[128 * 64];
  const int u = threadIdx.x;
  const int lane = u & 63;
  const int w = u >> 6;
  const int wr = w >> 1, wc = w & 1;
  const int m0 = blockIdx.y * 128;
  const int n0 = blockIdx.x * 128;
  const int r = lane & 15, q4 = lane >> 4;

  f32x4 acc[4][4];
  #pragma unroll
  for (int i = 0; i < 4; i++)
    #pragma unroll
    for (int j = 0; j < 4; j++) acc[i][j] = {0.f, 0.f, 0.f, 0.f};

  const int arow = u >> 3;        // 0..31
  const int acol = (u & 7) * 8;   // 0..56
  const u16* Ag = A + (size_t)(m0 + arow) * K + acol;
  const u16* Bg = Bt + (size_t)(n0 + arow) * K + acol;

  for (int k0 = 0; k0 < K; k0 += 64) {
    #pragma unroll
    for (int i = 0; i < 4; i++) {
      gload_lds16(Ag + (size_t)i * 32 * K + k0, &a_sh[(i * 32 + w * 8) * 64]);
      gload_lds16(Bg + (size_t)i * 32 * K + k0, &b_sh[(i * 32 + w * 8) * 64]);
    }
    __syncthreads();
    #pragma unroll
    for (int kc = 0; kc < 2; kc++) {
      bf16x8 af[4], bfr[4];
      #pragma unroll
      for (int m = 0; m < 4; m++)
        af[m] = *reinterpret_cast<const bf16x8*>(&a_sh[(wr * 64 + m * 16 + r) * 64 + kc * 32 + q4 * 8]);
      #pragma unroll
      for (int n = 0; n < 4; n++)
        bfr[n] = *reinterpret_cast<const bf16x8*>(&b_sh[(wc * 64 + n * 16 + r) * 64 + kc * 32 + q4 * 8]);
      #pragma unroll
      for (int m = 0; m < 4; m++)
        #pragma unroll
        for (int n = 0; n < 4; n++)
          acc[m][n] = __builtin_amdgcn_mfma_f32_16x16x32_bf16(af[m], bfr[n], acc[m][n], 0, 0, 0);
    }
    __syncthreads();
  }

  if (MODE == 0) {
    #pragma unroll
    for (int n = 0; n < 4; n++) {
      int gcol = n0 + wc * 64 + n * 16 + r;
      int which = gcol >> 10;   // uniform within fragment (16-aligned ranges)
      int rem = gcol & 1023;
      int h = rem >> 6, d = rem & 63;
      float bv = bias[gcol];
      #pragma unroll
      for (int m = 0; m < 4; m++) {
        #pragma unroll
        for (int reg = 0; reg < 4; reg++) {
          int grow = m0 + wr * 64 + m * 16 + q4 * 4 + reg;
          int b = grow >> 11, t = grow & 2047;
          u16 val = f2bf(acc[m][n][reg] + bv);
          if (which == 0)
            q_out[(((size_t)(b * NHEAD + h) * TT + t) << 6) + d] = val;
          else if (which == 1)
            k_out[(((size_t)(b * NHEAD + h) * TT + t) << 6) + d] = val;
          else  // V transposed: [b][h][d][t]
            v_out[(((size_t)(b * NHEAD + h) * HD + d) * TT) + t] = val;
        }
      }
    }
  } else {
    #pragma unroll
    for (int m = 0; m < 4; m++) {
      #pragma unroll
      for (int reg = 0; reg < 4; reg++) {
        int grow = m0 + wr * 64 + m * 16 + q4 * 4 + reg;
        #pragma unroll
        for (int n = 0; n < 4; n++) {
          int gcol = n0 + wc * 64 + n * 16 + r;
          c_out[(size_t)grow * N + gcol] = acc[m][n][reg] + bias[gcol];
        }
      }
    }
  }
}

// ---------------- causal flash attention, barrier-free ----------------
// grid: BB*NHEAD*32 blocks of 256. Each of the 4 waves is fully independent and
// owns 16 q-rows. Wave->q-tile map balances the causal triangle:
//   wt = (w<2) ? 2i+w : 127 - 2i - (w&1)      (i = blockIdx.x & 31)
// K read row-major from global (L2-resident), V read from pre-transposed Vt.
// P transpose goes through a PRIVATE per-wave LDS slice -> no __syncthreads anywhere.
__global__ __launch_bounds__(256)
void k_attn(const u16* __restrict__ Q, const u16* __restrict__ Kk,
            const u16* __restrict__ Vt, u16* __restrict__ Y)
{
  __shared__ __align__(16) u16 p_sh[4][16 * 72];

  const int u = threadIdx.x;
  const int lane = u & 63;
  const int w = u >> 6;
  const int r = lane & 15, q4 = lane >> 4;
  const int bh = blockIdx.x >> 5;
  const int i = blockIdx.x & 31;
  const int wt = (w < 2) ? (2 * i + w) : (127 - 2 * i - (w & 1));
  const int b = bh >> 4, h = bh & 15;
  const size_t head_off = (size_t)bh * TT * HD;   // Q,K: [t][d];  Vt: [d][t] (same byte extent)
  const int q0 = wt * 16;

  // Q fragments in registers for the whole task
  bf16x8 qf[2];
  qf[0] = *reinterpret_cast<const bf16x8*>(&Q[head_off + (size_t)(q0 + r) * HD + q4 * 8]);
  qf[1] = *reinterpret_cast<const bf16x8*>(&Q[head_off + (size_t)(q0 + r) * HD + 32 + q4 * 8]);

  f32x4 of[4];
  #pragma unroll
  for (int k = 0; k < 4; k++) of[k] = {0.f, 0.f, 0.f, 0.f};
  float m_run[4], l_run[4];
  #pragma unroll
  for (int k = 0; k < 4; k++) { m_run[k] = -1e30f; l_run[k] = 0.f; }

  const int lastkt = q0 >> 6;
  for (int kt = 0; kt <= lastkt; kt++) {
    // S = Q K^T : B-fragments straight from global
    f32x4 sf[4];
    #pragma unroll
    for (int n = 0; n < 4; n++) {
      f32x4 a = {0.f, 0.f, 0.f, 0.f};
      #pragma unroll
      for (int kc = 0; kc < 2; kc++) {
        bf16x8 kf = *reinterpret_cast<const bf16x8*>(
            &Kk[head_off + (size_t)(kt * 64 + n * 16 + r) * HD + kc * 32 + q4 * 8]);
        a = __builtin_amdgcn_mfma_f32_16x16x32_bf16(qf[kc], kf, a, 0, 0, 0);
      }
      sf[n] = a;
    }
    // scale + causal mask (only the diagonal tile needs it)
    #pragma unroll
    for (int n = 0; n < 4; n++) {
      #pragma unroll
      for (int reg = 0; reg < 4; reg++) {
        float s = sf[n][reg] * 0.125f;
        if (kt == lastkt) {
          int qg = q0 + q4 * 4 + reg;
          int kg = kt * 64 + n * 16 + r;
          if (kg > qg) s = -1e30f;
        }
        sf[n][reg] = s;
      }
    }
    // online softmax (row = q held across 16 lanes)
    float alpha[4];
    #pragma unroll
    for (int reg = 0; reg < 4; reg++) {
      float v = fmaxf(fmaxf(sf[0][reg], sf[1][reg]), fmaxf(sf[2][reg], sf[3][reg]));
      #pragma unroll
      for (int off = 1; off < 16; off <<= 1) v = fmaxf(v, __shfl_xor(v, off));
      float mnew = fmaxf(m_run[reg], v);
      alpha[reg] = __expf(m_run[reg] - mnew);
      m_run[reg] = mnew;
    }
    float rs[4] = {0.f, 0.f, 0.f, 0.f};
    #pragma unroll
    for (int n = 0; n < 4; n++) {
      #pragma unroll
      for (int reg = 0; reg < 4; reg++) {
        float p = __expf(sf[n][reg] - m_run[reg]);
        sf[n][reg] = p;
        rs[reg] += p;
      }
    }
    #pragma unroll
    for (int reg = 0; reg < 4; reg++) {
      float v = rs[reg];
      #pragma unroll
      for (int off = 1; off < 16; off <<= 1) v += __shfl_xor(v, off);
      l_run[reg] = l_run[reg] * alpha[reg] + v;
    }
    #pragma unroll
    for (int d0 = 0; d0 < 4; d0++)
      #pragma unroll
      for (int reg = 0; reg < 4; reg++)
        of[d0][reg] *= alpha[reg];

    // P transpose through this wave's private LDS slice (no barrier needed)
    #pragma unroll
    for (int n = 0; n < 4; n++)
      #pragma unroll
      for (int reg = 0; reg < 4; reg++)
        p_sh[w][(q4 * 4 + reg) * 72 + n * 16 + r] = f2bf(sf[n][reg]);

    // O += P @ V : V B-fragments straight from transposed global Vt
    #pragma unroll
    for (int kc = 0; kc < 2; kc++) {
      bf16x8 pa = *reinterpret_cast<const bf16x8*>(&p_sh[w][r * 72 + kc * 32 + q4 * 8]);
      #pragma unroll
      for (int d0 = 0; d0 < 4; d0++) {
        bf16x8 vb = *reinterpret_cast<const bf16x8*>(
            &Vt[head_off + (size_t)(d0 * 16 + r) * TT + kt * 64 + kc * 32 + q4 * 8]);
        of[d0] = __builtin_amdgcn_mfma_f32_16x16x32_bf16(pa, vb, of[d0], 0, 0, 0);
      }
    }
  }

  // epilogue: Y[(b*T + t)*1024 + h*64 + d], bf16
  #pragma unroll
  for (int d0 = 0; d0 < 4; d0++) {
    #pragma unroll
    for (int reg = 0; reg < 4; reg++) {
      int t = q0 + q4 * 4 + reg;
      float val = of[d0][reg] / l_run[reg];
      Y[((size_t)(b * TT + t) << 10) + h * 64 + d0 * 16 + r] = f2bf(val);
    }
  }
}

// ---------------- host launcher ----------------
extern "C" void kernel_launch(void* const* d_in, const int* in_sizes, int n_in,
                              void* d_out, int out_size, void* d_ws, size_t ws_size,
                              hipStream_t stream) {
  const float* x     = (const float*)d_in[0];
  const float* w_qkv = (const float*)d_in[1];
  const float* b_qkv = (const float*)d_in[2];
  const float* w_out = (const float*)d_in[3];
  const float* b_out = (const float*)d_in[4];
  float* out = (float*)d_out;

  uint8_t* ws = (uint8_t*)d_ws;
  u16* xb    = (u16*)(ws);                    // 8 MB  (reused as y_heads later)
  u16* wqkvT = (u16*)(ws + (8u  << 20));      // 6 MB
  u16* woutT = (u16*)(ws + (14u << 20));      // 2 MB
  u16* Qh    = (u16*)(ws + (16u << 20));      // 8 MB
  u16* Kh    = (u16*)(ws + (24u << 20));      // 8 MB
  u16* Vth   = (u16*)(ws + (32u << 20));      // 8 MB  (transposed V)

  k_f32_to_bf16<<<1024, 256, 0, stream>>>(x, xb, (MR * D_MODEL) / 4);
  k_transpose_f32_bf16<<<dim3(3 * D_MODEL / 32, D_MODEL / 32), dim3(32, 8), 0, stream>>>(
      w_qkv, wqkvT, D_MODEL, 3 * D_MODEL);
  k_transpose_f32_bf16<<<dim3(D_MODEL / 32, D_MODEL / 32), dim3(32, 8), 0, stream>>>(
      w_out, woutT, D_MODEL, D_MODEL);

  k_gemm_bt<0><<<dim3(3 * D_MODEL / 128, MR / 128), 256, 0, stream>>>(
      xb, wqkvT, b_qkv, Qh, Kh, Vth, nullptr, MR, 3 * D_MODEL, D_MODEL);

  u16* Yh = xb;  // reuse x-bf16 region
  k_attn<<<dim3(BB * NHEAD * 32), 256, 0, stream>>>(Qh, Kh, Vth, Yh);

  k_gemm_bt<1><<<dim3(D_MODEL / 128, MR / 128), 256, 0, stream>>>(
      Yh, woutT, b_out, nullptr, nullptr, nullptr, out, MR, D_MODEL, D_MODEL);
}